// Round 1
// baseline (170.700 us; speedup 1.0000x reference)
//
#include <hip/hip_runtime.h>
#include <math.h>

#define B_ 8
#define N_ 2048
#define C_ 512
#define G_ 32          // chunks per batch
#define L_ 64          // chunk length = N_/G_

// ---- workspace layout (in floats) ----
static const size_t OFF_V1   = 0;                    // 512
static const size_t OFF_V2   = OFF_V1 + 512;         // 512
static const size_t OFF_S1   = OFF_V2 + 512;         // B*N = 16384
static const size_t OFF_S2   = OFF_S1 + 16384;       // 16384
static const size_t OFF_Z    = OFF_S2 + 16384;       // 16384 (sorted s2)
static const size_t OFF_IDX  = OFF_Z + 16384;        // 16384 (int perm)
static const size_t OFF_P    = OFF_IDX + 16384;      // 16384  p = exp(z-m2)
static const size_t OFF_Q    = OFF_P + 16384;        // 16384  q = exp(0.2(z-m2))
static const size_t OFF_PPRE = OFF_Q + 16384;        // B*(N+1) scalar prefix of p (pad to 16400)
static const size_t OFF_QPRE = OFF_PPRE + 16400;     // B*(N+1) scalar prefix of q
static const size_t OFF_CHP  = OFF_QPRE + 16400;     // B*G*C = 131072 chunk P sums -> suffix offsets
static const size_t OFF_CHQ  = OFF_CHP + 131072;     // chunk Q sums -> prefix offsets
static const size_t OFF_BIGP = OFF_CHQ + 131072;     // B*N*C suffix cumsum of p*x
static const size_t OFF_BIGQ = OFF_BIGP + 8388608;   // B*N*C prefix cumsum of q*x
// total = OFF_BIGQ + 8388608 = 17,171,488 floats ~= 68.7 MB

// K1: v1 = w @ a1, v2 = w @ a2  (one 64-lane wave per row of w)
__global__ __launch_bounds__(64) void k_wa(const float* __restrict__ w,
                                           const float* __restrict__ a,
                                           float* __restrict__ v1, float* __restrict__ v2) {
    int k = blockIdx.x, lane = threadIdx.x;
    float acc1 = 0.f, acc2 = 0.f;
    for (int c = lane; c < C_; c += 64) {
        float wv = w[k * C_ + c];
        acc1 += wv * a[c];
        acc2 += wv * a[C_ + c];
    }
    for (int o = 32; o > 0; o >>= 1) { acc1 += __shfl_down(acc1, o); acc2 += __shfl_down(acc2, o); }
    if (lane == 0) { v1[k] = acc1; v2[k] = acc2; }
}

// K2: s1[r] = x[r,:]·v1, s2[r] = x[r,:]·v2  (one wave per row, 4 waves/block)
__global__ __launch_bounds__(256) void k_s(const float* __restrict__ x,
                                           const float* __restrict__ v1,
                                           const float* __restrict__ v2,
                                           float* __restrict__ s1, float* __restrict__ s2) {
    __shared__ __align__(16) float sv1[C_];
    __shared__ __align__(16) float sv2[C_];
    int tid = threadIdx.x;
    for (int c = tid; c < C_; c += 256) { sv1[c] = v1[c]; sv2[c] = v2[c]; }
    __syncthreads();
    int wave = tid >> 6, lane = tid & 63;
    int r = blockIdx.x * 4 + wave;                       // [0, 16384)
    const float4* xr = reinterpret_cast<const float4*>(x + (size_t)r * C_);
    const float4* w1p = reinterpret_cast<const float4*>(sv1);
    const float4* w2p = reinterpret_cast<const float4*>(sv2);
    float a1 = 0.f, a2 = 0.f;
    for (int half = 0; half < 2; ++half) {
        int c4 = lane + half * 64;
        float4 xv = xr[c4];
        float4 w1 = w1p[c4];
        float4 w2 = w2p[c4];
        a1 += xv.x*w1.x + xv.y*w1.y + xv.z*w1.z + xv.w*w1.w;
        a2 += xv.x*w2.x + xv.y*w2.y + xv.z*w2.z + xv.w*w2.w;
    }
    for (int o = 32; o > 0; o >>= 1) { a1 += __shfl_down(a1, o); a2 += __shfl_down(a2, o); }
    if (lane == 0) { s1[r] = a1; s2[r] = a2; }
}

// K3: per-batch bitonic sort of s2 (values + perm), p/q, and scalar prefix scans
__global__ __launch_bounds__(1024) void k_sort(const float* __restrict__ s2,
                                               float* __restrict__ z, int* __restrict__ idxArr,
                                               float* __restrict__ pArr, float* __restrict__ qArr,
                                               float* __restrict__ Ppre, float* __restrict__ Qpre) {
    __shared__ float sval[N_];
    __shared__ int   sidx[N_];
    __shared__ float sp[N_];
    __shared__ float sq[N_];
    __shared__ float scan[1024];
    int b = blockIdx.x, tid = threadIdx.x;
    for (int e = tid; e < N_; e += 1024) { sval[e] = s2[b * N_ + e]; sidx[e] = e; }
    __syncthreads();
    for (unsigned k = 2; k <= (unsigned)N_; k <<= 1) {
        for (unsigned j = k >> 1; j > 0; j >>= 1) {
            for (unsigned i = tid; i < (unsigned)N_; i += 1024) {
                unsigned l = i ^ j;
                if (l > i) {
                    bool asc = ((i & k) == 0);
                    float vi = sval[i], vl = sval[l];
                    if ((vi > vl) == asc) {
                        sval[i] = vl; sval[l] = vi;
                        int ti = sidx[i]; sidx[i] = sidx[l]; sidx[l] = ti;
                    }
                }
            }
            __syncthreads();
        }
    }
    float m2 = sval[N_ - 1];
    for (int e = tid; e < N_; e += 1024) {
        float d  = sval[e] - m2;
        float pv = __expf(d);
        float qv = __expf(0.2f * d);
        sp[e] = pv; sq[e] = qv;
        z[b * N_ + e]      = sval[e];
        idxArr[b * N_ + e] = sidx[e];
        pArr[b * N_ + e]   = pv;
        qArr[b * N_ + e]   = qv;
    }
    __syncthreads();
    // scalar exclusive prefix of p -> Ppre[b][0..N]
    {
        float pair = sp[2 * tid] + sp[2 * tid + 1];
        scan[tid] = pair;
        __syncthreads();
        for (int off = 1; off < 1024; off <<= 1) {
            float t = 0.f;
            if (tid >= off) t = scan[tid - off];
            __syncthreads();
            if (tid >= off) scan[tid] += t;
            __syncthreads();
        }
        float incl = scan[tid];
        float excl = incl - pair;
        Ppre[b * 2049 + 2 * tid]     = excl;
        Ppre[b * 2049 + 2 * tid + 1] = excl + sp[2 * tid];
        if (tid == 1023) Ppre[b * 2049 + N_] = incl;
        __syncthreads();
    }
    // scalar exclusive prefix of q -> Qpre[b][0..N]
    {
        float pair = sq[2 * tid] + sq[2 * tid + 1];
        scan[tid] = pair;
        __syncthreads();
        for (int off = 1; off < 1024; off <<= 1) {
            float t = 0.f;
            if (tid >= off) t = scan[tid - off];
            __syncthreads();
            if (tid >= off) scan[tid] += t;
            __syncthreads();
        }
        float incl = scan[tid];
        float excl = incl - pair;
        Qpre[b * 2049 + 2 * tid]     = excl;
        Qpre[b * 2049 + 2 * tid + 1] = excl + sq[2 * tid];
        if (tid == 1023) Qpre[b * 2049 + N_] = incl;
    }
}

// K4a: per-chunk vector sums  chP[b,g,c] = sum_{j in g} p_j x[idx_j, c]  (same for Q)
__global__ __launch_bounds__(512) void k_chunk(const float* __restrict__ x,
                                               const int* __restrict__ idxArr,
                                               const float* __restrict__ pArr,
                                               const float* __restrict__ qArr,
                                               float* __restrict__ chP, float* __restrict__ chQ) {
    int bg = blockIdx.x, b = bg >> 5, g = bg & 31;
    int c = threadIdx.x;
    __shared__ int   srow[L_];
    __shared__ float spv[L_], sqv[L_];
    if (c < L_) {
        int j = g * L_ + c;
        srow[c] = idxArr[b * N_ + j];
        spv[c]  = pArr[b * N_ + j];
        sqv[c]  = qArr[b * N_ + j];
    }
    __syncthreads();
    const float* xb = x + (size_t)b * N_ * C_;
    float accP = 0.f, accQ = 0.f;
    for (int t = 0; t < L_; ++t) {
        float xv = xb[(size_t)srow[t] * C_ + c];
        accP += spv[t] * xv;
        accQ += sqv[t] * xv;
    }
    chP[(size_t)bg * C_ + c] = accP;
    chQ[(size_t)bg * C_ + c] = accQ;
}

// K4b: turn chunk sums into exclusive suffix (P) / prefix (Q) offsets, in place
__global__ __launch_bounds__(512) void k_choff(float* __restrict__ chP, float* __restrict__ chQ) {
    int b = blockIdx.x, c = threadIdx.x;
    float run = 0.f;
    for (int g = G_ - 1; g >= 0; --g) {
        size_t id = ((size_t)(b * G_ + g)) * C_ + c;
        float t = chP[id]; chP[id] = run; run += t;
    }
    run = 0.f;
    for (int g = 0; g < G_; ++g) {
        size_t id = ((size_t)(b * G_ + g)) * C_ + c;
        float t = chQ[id]; chQ[id] = run; run += t;
    }
}

// K4c: full vector cumsums.
// bigP[b,j,c] = sum_{j'>=j} p_j' x[idx_j',c]   (suffix, stored at sorted pos j)
// bigQ[b,j,c] = sum_{j'<=j} q_j' x[idx_j',c]   (prefix inclusive = PreQ[j+1])
__global__ __launch_bounds__(512) void k_cumsum(const float* __restrict__ x,
                                                const int* __restrict__ idxArr,
                                                const float* __restrict__ pArr,
                                                const float* __restrict__ qArr,
                                                const float* __restrict__ chP,
                                                const float* __restrict__ chQ,
                                                float* __restrict__ bigP, float* __restrict__ bigQ) {
    int bg = blockIdx.x, b = bg >> 5, g = bg & 31;
    int c = threadIdx.x;
    __shared__ int   srow[L_];
    __shared__ float spv[L_], sqv[L_];
    if (c < L_) {
        int j = g * L_ + c;
        srow[c] = idxArr[b * N_ + j];
        spv[c]  = pArr[b * N_ + j];
        sqv[c]  = qArr[b * N_ + j];
    }
    __syncthreads();
    const float* xb = x + (size_t)b * N_ * C_;
    float runP = chP[(size_t)bg * C_ + c];
    for (int t = L_ - 1; t >= 0; --t) {
        int j = g * L_ + t;
        runP += spv[t] * xb[(size_t)srow[t] * C_ + c];
        bigP[((size_t)b * N_ + j) * C_ + c] = runP;
    }
    float runQ = chQ[(size_t)bg * C_ + c];
    for (int t = 0; t < L_; ++t) {
        int j = g * L_ + t;
        runQ += sqv[t] * xb[(size_t)srow[t] * C_ + c];
        bigQ[((size_t)b * N_ + j) * C_ + c] = runQ;
    }
}

// K5: per output row: binary search split point, combine two cumsum rows
__global__ __launch_bounds__(256) void k_out(const float* __restrict__ s1,
                                             const float* __restrict__ z,
                                             const float* __restrict__ Ppre,
                                             const float* __restrict__ Qpre,
                                             const float* __restrict__ bigP,
                                             const float* __restrict__ bigQ,
                                             float* __restrict__ out) {
    int tid = threadIdx.x, wave = tid >> 6, lane = tid & 63;
    int r = blockIdx.x * 4 + wave;        // [0, 16384)
    int b = r >> 11;
    float s1v = s1[r];
    const float* zb = z + (size_t)b * N_;
    float m2  = zb[N_ - 1];
    float thr = -s1v;
    int lo = 0, hi = N_;
    while (lo < hi) {                      // lower_bound: first z >= thr
        int mid = (lo + hi) >> 1;
        if (zb[mid] >= thr) hi = mid; else lo = mid + 1;
    }
    int k = lo;
    float beta = s1v + m2;
    float wP, wQ;
    if (beta >= 0.f) { wP = 1.f;               wQ = __expf(-0.8f * beta); }
    else             { wP = __expf(0.8f * beta); wQ = 1.f; }
    float Sp = Ppre[b * 2049 + N_] - Ppre[b * 2049 + k];
    float Sq = Qpre[b * 2049 + k];
    float inv = 1.0f / (wP * Sp + wQ * Sq);
    float fP = wP * inv, fQ = wQ * inv;
    const float4* rowP = (k < N_) ? reinterpret_cast<const float4*>(bigP + ((size_t)b * N_ + k) * C_) : nullptr;
    const float4* rowQ = (k > 0)  ? reinterpret_cast<const float4*>(bigQ + ((size_t)b * N_ + k - 1) * C_) : nullptr;
    float4* orow = reinterpret_cast<float4*>(out + (size_t)r * C_);
    for (int half = 0; half < 2; ++half) {
        int c4 = lane + half * 64;
        float4 Pv = rowP ? rowP[c4] : make_float4(0.f, 0.f, 0.f, 0.f);
        float4 Qv = rowQ ? rowQ[c4] : make_float4(0.f, 0.f, 0.f, 0.f);
        float4 o;
        o.x = fP * Pv.x + fQ * Qv.x;
        o.y = fP * Pv.y + fQ * Qv.y;
        o.z = fP * Pv.z + fQ * Qv.z;
        o.w = fP * Pv.w + fQ * Qv.w;
        orow[c4] = o;
    }
}

extern "C" void kernel_launch(void* const* d_in, const int* in_sizes, int n_in,
                              void* d_out, int out_size, void* d_ws, size_t ws_size,
                              hipStream_t stream) {
    const float* x = (const float*)d_in[0];   // (B,N,C)
    const float* w = (const float*)d_in[1];   // (C,C)
    const float* a = (const float*)d_in[2];   // (2C,1)
    float* out = (float*)d_out;
    float* ws  = (float*)d_ws;

    float* v1   = ws + OFF_V1;
    float* v2   = ws + OFF_V2;
    float* s1   = ws + OFF_S1;
    float* s2   = ws + OFF_S2;
    float* zArr = ws + OFF_Z;
    int*   idxA = (int*)(ws + OFF_IDX);
    float* pArr = ws + OFF_P;
    float* qArr = ws + OFF_Q;
    float* Ppre = ws + OFF_PPRE;
    float* Qpre = ws + OFF_QPRE;
    float* chP  = ws + OFF_CHP;
    float* chQ  = ws + OFF_CHQ;
    float* bigP = ws + OFF_BIGP;
    float* bigQ = ws + OFF_BIGQ;

    k_wa    <<<dim3(C_),        dim3(64),   0, stream>>>(w, a, v1, v2);
    k_s     <<<dim3(4096),      dim3(256),  0, stream>>>(x, v1, v2, s1, s2);
    k_sort  <<<dim3(B_),        dim3(1024), 0, stream>>>(s2, zArr, idxA, pArr, qArr, Ppre, Qpre);
    k_chunk <<<dim3(B_ * G_),   dim3(512),  0, stream>>>(x, idxA, pArr, qArr, chP, chQ);
    k_choff <<<dim3(B_),        dim3(512),  0, stream>>>(chP, chQ);
    k_cumsum<<<dim3(B_ * G_),   dim3(512),  0, stream>>>(x, idxA, pArr, qArr, chP, chQ, bigP, bigQ);
    k_out   <<<dim3(4096),      dim3(256),  0, stream>>>(s1, zArr, Ppre, Qpre, bigP, bigQ, out);
}

// Round 2
// 148.764 us; speedup vs baseline: 1.1475x; 1.1475x over previous
//
#include <hip/hip_runtime.h>
#include <math.h>

#define B_ 8
#define N_ 2048
#define C_ 512
#define G_ 32          // chunks per batch
#define L_ 64          // chunk length = N_/G_

// ---- workspace layout (in floats) ----
static const size_t OFF_V1   = 0;                    // 512
static const size_t OFF_V2   = OFF_V1 + 512;         // 512
static const size_t OFF_S1   = OFF_V2 + 512;         // 16384
static const size_t OFF_S2   = OFF_S1 + 16384;       // 16384
static const size_t OFF_Z    = OFF_S2 + 16384;       // 16384 sorted s2
static const size_t OFF_IDX  = OFF_Z + 16384;        // 16384 perm
static const size_t OFF_P    = OFF_IDX + 16384;      // 16384 p = exp(z-m2)
static const size_t OFF_Q    = OFF_P + 16384;        // 16384 q = exp(0.2(z-m2))
static const size_t OFF_PPRE = OFF_Q + 16384;        // 16400 scalar prefix p
static const size_t OFF_QPRE = OFF_PPRE + 16400;     // 16400 scalar prefix q
static const size_t OFF_CHP  = OFF_QPRE + 16400;     // 131072 chunk P sums -> suffix offsets
static const size_t OFF_CHQ  = OFF_CHP + 131072;     // 131072 chunk Q sums -> suffix offsets
static const size_t OFF_TOTQ = OFF_CHQ + 131072;     // 4096 per-(b,c) total Q
static const size_t OFF_BIGE = OFF_TOTQ + 4096;      // 8*2049*512*2 = 16,785,408 (float2 rows)
// total ~= 17.2M floats ~= 68.7 MB

// K1: v1 = w @ a1, v2 = w @ a2
__global__ __launch_bounds__(64) void k_wa(const float* __restrict__ w,
                                           const float* __restrict__ a,
                                           float* __restrict__ v1, float* __restrict__ v2) {
    int k = blockIdx.x, lane = threadIdx.x;
    float acc1 = 0.f, acc2 = 0.f;
    for (int c = lane; c < C_; c += 64) {
        float wv = w[k * C_ + c];
        acc1 += wv * a[c];
        acc2 += wv * a[C_ + c];
    }
    for (int o = 32; o > 0; o >>= 1) { acc1 += __shfl_down(acc1, o); acc2 += __shfl_down(acc2, o); }
    if (lane == 0) { v1[k] = acc1; v2[k] = acc2; }
}

// K2: s1[r] = x[r,:]·v1, s2[r] = x[r,:]·v2
__global__ __launch_bounds__(256) void k_s(const float* __restrict__ x,
                                           const float* __restrict__ v1,
                                           const float* __restrict__ v2,
                                           float* __restrict__ s1, float* __restrict__ s2) {
    __shared__ __align__(16) float sv1[C_];
    __shared__ __align__(16) float sv2[C_];
    int tid = threadIdx.x;
    for (int c = tid; c < C_; c += 256) { sv1[c] = v1[c]; sv2[c] = v2[c]; }
    __syncthreads();
    int wave = tid >> 6, lane = tid & 63;
    int r = blockIdx.x * 4 + wave;
    const float4* xr  = reinterpret_cast<const float4*>(x + (size_t)r * C_);
    const float4* w1p = reinterpret_cast<const float4*>(sv1);
    const float4* w2p = reinterpret_cast<const float4*>(sv2);
    float a1 = 0.f, a2 = 0.f;
    for (int half = 0; half < 2; ++half) {
        int c4 = lane + half * 64;
        float4 xv = xr[c4], w1 = w1p[c4], w2 = w2p[c4];
        a1 += xv.x*w1.x + xv.y*w1.y + xv.z*w1.z + xv.w*w1.w;
        a2 += xv.x*w2.x + xv.y*w2.y + xv.z*w2.z + xv.w*w2.w;
    }
    for (int o = 32; o > 0; o >>= 1) { a1 += __shfl_down(a1, o); a2 += __shfl_down(a2, o); }
    if (lane == 0) { s1[r] = a1; s2[r] = a2; }
}

// K3: rank-by-counting "sort": exact permutation + p/q.
// 256 blocks: (b, grp) grp handles 64 elements; 4 quarter-threads per element each
// count comparisons over 512 of the 2048 values.
__global__ __launch_bounds__(256) void k_rank(const float* __restrict__ s2,
                                              float* __restrict__ z, int* __restrict__ idxArr,
                                              float* __restrict__ pArr, float* __restrict__ qArr) {
    __shared__ float sval[N_];
    __shared__ float sred[256];
    __shared__ int   srnk[256];
    int blk = blockIdx.x;
    int b = blk >> 5, grp = blk & 31;
    int tid = threadIdx.x;
    int le = tid & 63, qtr = tid >> 6;
    for (int i = tid; i < N_; i += 256) sval[i] = s2[(size_t)b * N_ + i];
    __syncthreads();
    int e = grp * 64 + le;
    float val = sval[e];
    int base = qtr * 512;
    int rank = 0;
    float mx = -3.4e38f;
    #pragma unroll 8
    for (int i = 0; i < 512; ++i) {
        int t = base + i;
        float v = sval[t];
        mx = fmaxf(mx, v);
        rank += (v < val) || (v == val && t < e);
    }
    srnk[tid] = rank;
    sred[tid] = mx;
    __syncthreads();
    for (int o = 128; o > 0; o >>= 1) {
        if (tid < o) sred[tid] = fmaxf(sred[tid], sred[tid + o]);
        __syncthreads();
    }
    float m2 = sred[0];
    if (qtr == 0) {
        int rk = srnk[le] + srnk[le + 64] + srnk[le + 128] + srnk[le + 192];
        float d = val - m2;
        size_t pos = (size_t)b * N_ + rk;
        z[pos]      = val;
        idxArr[pos] = e;
        pArr[pos]   = __expf(d);
        qArr[pos]   = __expf(0.2f * d);
    }
}

// K4: scalar exclusive prefixes of p and q (3 barriers, shfl scan)
__global__ __launch_bounds__(1024) void k_scan(const float* __restrict__ pArr,
                                               const float* __restrict__ qArr,
                                               float* __restrict__ Ppre, float* __restrict__ Qpre) {
    __shared__ float wsP[16], wsQ[16], woP[16], woQ[16];
    int b = blockIdx.x, tid = threadIdx.x, lane = tid & 63, wid = tid >> 6;
    size_t ib = (size_t)b * N_;
    float p0 = pArr[ib + 2 * tid], p1 = pArr[ib + 2 * tid + 1];
    float q0 = qArr[ib + 2 * tid], q1 = qArr[ib + 2 * tid + 1];
    float pv = p0 + p1, qv = q0 + q1;
    float pi = pv, qi = qv;
    for (int o = 1; o < 64; o <<= 1) {
        float tp = __shfl_up(pi, o), tq = __shfl_up(qi, o);
        if (lane >= o) { pi += tp; qi += tq; }
    }
    if (lane == 63) { wsP[wid] = pi; wsQ[wid] = qi; }
    __syncthreads();
    if (wid == 0 && lane < 16) {
        float sp = wsP[lane], sq = wsQ[lane];
        float ip = sp, iq = sq;
        for (int o = 1; o < 16; o <<= 1) {
            float tp = __shfl_up(ip, o), tq = __shfl_up(iq, o);
            if (lane >= o) { ip += tp; iq += tq; }
        }
        woP[lane] = ip - sp; woQ[lane] = iq - sq;
    }
    __syncthreads();
    float inclP = pi + woP[wid], inclQ = qi + woQ[wid];
    float exclP = inclP - pv, exclQ = inclQ - qv;
    size_t base = (size_t)b * 2049;
    Ppre[base + 2 * tid]     = exclP;
    Ppre[base + 2 * tid + 1] = exclP + p0;
    Qpre[base + 2 * tid]     = exclQ;
    Qpre[base + 2 * tid + 1] = exclQ + q0;
    if (tid == 1023) { Ppre[base + N_] = inclP; Qpre[base + N_] = inclQ; }
}

// K5: per-chunk vector sums chP/chQ[b,g,c]
__global__ __launch_bounds__(512) void k_chunk(const float* __restrict__ x,
                                               const int* __restrict__ idxArr,
                                               const float* __restrict__ pArr,
                                               const float* __restrict__ qArr,
                                               float* __restrict__ chP, float* __restrict__ chQ) {
    int bg = blockIdx.x, b = bg >> 5, g = bg & 31;
    int c = threadIdx.x;
    __shared__ int   srow[L_];
    __shared__ float spv[L_], sqv[L_];
    if (c < L_) {
        int j = g * L_ + c;
        srow[c] = idxArr[b * N_ + j];
        spv[c]  = pArr[b * N_ + j];
        sqv[c]  = qArr[b * N_ + j];
    }
    __syncthreads();
    const float* xb = x + (size_t)b * N_ * C_;
    float accP = 0.f, accQ = 0.f;
    for (int t = 0; t < L_; ++t) {
        float xv = xb[(size_t)srow[t] * C_ + c];
        accP += spv[t] * xv;
        accQ += sqv[t] * xv;
    }
    chP[(size_t)bg * C_ + c] = accP;
    chQ[(size_t)bg * C_ + c] = accQ;
}

// K6: chunk sums -> exclusive SUFFIX offsets (both P and Q), plus per-(b,c) total Q.
// Load all 32 into registers (independent loads), scan in-register, write back.
__global__ __launch_bounds__(512) void k_choff(float* __restrict__ chP, float* __restrict__ chQ,
                                               float* __restrict__ totQ) {
    int b = blockIdx.x, c = threadIdx.x;
    float vP[G_], vQ[G_];
    #pragma unroll
    for (int g = 0; g < G_; ++g) {
        size_t id = ((size_t)(b * G_ + g)) * C_ + c;
        vP[g] = chP[id];
        vQ[g] = chQ[id];
    }
    float runP = 0.f, runQ = 0.f;
    #pragma unroll
    for (int g = G_ - 1; g >= 0; --g) {
        size_t id = ((size_t)(b * G_ + g)) * C_ + c;
        float tP = vP[g], tQ = vQ[g];
        chP[id] = runP; chQ[id] = runQ;
        runP += tP; runQ += tQ;
    }
    totQ[b * C_ + c] = runQ;
}

// K7: single suffix walk writing interleaved rows:
//   bigE[b, j, c] = ( SufP[j,c], TotQ[c] - SufQ[j,c] ) = ( suffix p·x, exclusive-prefix q·x )
// Row N (= all-Q split) written by chunk G-1 at walk start.
__global__ __launch_bounds__(512) void k_cumsum(const float* __restrict__ x,
                                                const int* __restrict__ idxArr,
                                                const float* __restrict__ pArr,
                                                const float* __restrict__ qArr,
                                                const float* __restrict__ chP,
                                                const float* __restrict__ chQ,
                                                const float* __restrict__ totQ,
                                                float2* __restrict__ bigE) {
    int bg = blockIdx.x, b = bg >> 5, g = bg & 31;
    int c = threadIdx.x;
    __shared__ int   srow[L_];
    __shared__ float spv[L_], sqv[L_];
    if (c < L_) {
        int j = g * L_ + c;
        srow[c] = idxArr[b * N_ + j];
        spv[c]  = pArr[b * N_ + j];
        sqv[c]  = qArr[b * N_ + j];
    }
    __syncthreads();
    const float* xb = x + (size_t)b * N_ * C_;
    float runP = chP[(size_t)bg * C_ + c];
    float runQ = chQ[(size_t)bg * C_ + c];
    float tq   = totQ[b * C_ + c];
    float2* bigEb = bigE + (size_t)b * (N_ + 1) * C_;
    if (g == G_ - 1) bigEb[(size_t)N_ * C_ + c] = make_float2(0.f, tq);
    for (int t = L_ - 1; t >= 0; --t) {
        int j = g * L_ + t;
        float xv = xb[(size_t)srow[t] * C_ + c];
        runP += spv[t] * xv;
        runQ += sqv[t] * xv;
        bigEb[(size_t)j * C_ + c] = make_float2(runP, tq - runQ);
    }
}

// K8: binary search split, read ONE contiguous bigE row, write output row.
__global__ __launch_bounds__(256) void k_out(const float* __restrict__ s1,
                                             const float* __restrict__ z,
                                             const float* __restrict__ Ppre,
                                             const float* __restrict__ Qpre,
                                             const float2* __restrict__ bigE,
                                             float* __restrict__ out) {
    int tid = threadIdx.x, wave = tid >> 6, lane = tid & 63;
    int r = blockIdx.x * 4 + wave;
    int b = r >> 11;
    float s1v = s1[r];
    const float* zb = z + (size_t)b * N_;
    float m2  = zb[N_ - 1];
    float thr = -s1v;
    int lo = 0, hi = N_;
    while (lo < hi) {
        int mid = (lo + hi) >> 1;
        if (zb[mid] >= thr) hi = mid; else lo = mid + 1;
    }
    int k = lo;
    float beta = s1v + m2;
    float wP, wQ;
    if (beta >= 0.f) { wP = 1.f;                 wQ = __expf(-0.8f * beta); }
    else             { wP = __expf(0.8f * beta); wQ = 1.f; }
    float Sp = Ppre[b * 2049 + N_] - Ppre[b * 2049 + k];
    float Sq = Qpre[b * 2049 + k];
    float inv = 1.0f / (wP * Sp + wQ * Sq);
    float fP = wP * inv, fQ = wQ * inv;
    const float4* row4 = reinterpret_cast<const float4*>(bigE + ((size_t)b * (N_ + 1) + k) * C_);
    float2* orow = reinterpret_cast<float2*>(out + (size_t)r * C_);
    #pragma unroll
    for (int half = 0; half < 4; ++half) {
        int c4 = lane + half * 64;               // pair index, covers channels 2c4, 2c4+1
        float4 E = row4[c4];
        orow[c4] = make_float2(fP * E.x + fQ * E.y, fP * E.z + fQ * E.w);
    }
}

extern "C" void kernel_launch(void* const* d_in, const int* in_sizes, int n_in,
                              void* d_out, int out_size, void* d_ws, size_t ws_size,
                              hipStream_t stream) {
    const float* x = (const float*)d_in[0];
    const float* w = (const float*)d_in[1];
    const float* a = (const float*)d_in[2];
    float* out = (float*)d_out;
    float* ws  = (float*)d_ws;

    float*  v1   = ws + OFF_V1;
    float*  v2   = ws + OFF_V2;
    float*  s1   = ws + OFF_S1;
    float*  s2   = ws + OFF_S2;
    float*  zArr = ws + OFF_Z;
    int*    idxA = (int*)(ws + OFF_IDX);
    float*  pArr = ws + OFF_P;
    float*  qArr = ws + OFF_Q;
    float*  Ppre = ws + OFF_PPRE;
    float*  Qpre = ws + OFF_QPRE;
    float*  chP  = ws + OFF_CHP;
    float*  chQ  = ws + OFF_CHQ;
    float*  totQ = ws + OFF_TOTQ;
    float2* bigE = (float2*)(ws + OFF_BIGE);

    k_wa    <<<dim3(C_),      dim3(64),   0, stream>>>(w, a, v1, v2);
    k_s     <<<dim3(4096),    dim3(256),  0, stream>>>(x, v1, v2, s1, s2);
    k_rank  <<<dim3(B_ * 32), dim3(256),  0, stream>>>(s2, zArr, idxA, pArr, qArr);
    k_scan  <<<dim3(B_),      dim3(1024), 0, stream>>>(pArr, qArr, Ppre, Qpre);
    k_chunk <<<dim3(B_ * G_), dim3(512),  0, stream>>>(x, idxA, pArr, qArr, chP, chQ);
    k_choff <<<dim3(B_),      dim3(512),  0, stream>>>(chP, chQ, totQ);
    k_cumsum<<<dim3(B_ * G_), dim3(512),  0, stream>>>(x, idxA, pArr, qArr, chP, chQ, totQ, bigE);
    k_out   <<<dim3(4096),    dim3(256),  0, stream>>>(s1, zArr, Ppre, Qpre, bigE, out);
}